// Round 6
// baseline (149.453 us; speedup 1.0000x reference)
//
#include <hip/hip_runtime.h>

#define B_ 8
#define H_ 512
#define W_ 1024
#define NPX (B_*H_*W_)

// ---------------- Stage 1 geometry ----------------
#define TILE 32
#define HD 4
#define RD 40
#define HB 7
#define RB 46
#define HP 8
#define RP 48

__device__ __forceinline__ int clampi(int v, int lo, int hi) {
    return v < lo ? lo : (v > hi ? hi : v);
}
__device__ __forceinline__ int imax(int a, int b) { return a > b ? a : b; }
__device__ __forceinline__ int imin(int a, int b) { return a < b ? a : b; }

// K1: per-tile identity check (every in-image px of tile+1 halo is a boundary px).
// Clean: write flag=0 (flags mode) or copy x->mid (copy mode). Dirty: general path + flag=1.
__global__ __launch_bounds__(256)
void k_stage1(const float* __restrict__ xg, const int* __restrict__ predg,
              float* __restrict__ midg, unsigned char* __restrict__ flags)
{
    __shared__ int sScratch[3200];              // union: pred 36x40 / pred 48x48 / sHX+sHM
    __shared__ unsigned long long sB[4][RB];
    __shared__ float sA[RD * RD];
    __shared__ float sC[RD * RD];
    __shared__ int sV[4];

    int*   sPred = sScratch;
    float* sHX = (float*)sScratch;
    float* sHM = (float*)sScratch + RD * RD;

    const int tid = threadIdx.x;
    const int x0 = blockIdx.x * TILE;
    const int y0 = blockIdx.y * TILE;
    const size_t plane = (size_t)H_ * W_;
    const int*   pp = predg + blockIdx.z * plane;
    const float* xp = xg    + blockIdx.z * plane;
    float*       op = midg  + blockIdx.z * plane;

    const bool leftB  = (x0 == 0), rightB = (x0 + TILE == W_);
    const bool topB   = (y0 == 0), botB   = (y0 + TILE == H_);
    const bool borderB = leftB || rightB || topB || botB;

    // ---- load pred region rows y0-2..y0+33, cols x0-4..x0+35 into sPred[36][40] ----
    if (!borderB) {
        for (int i = tid; i < 36 * 10; i += 256) {
            int ry = i / 10, c4 = i - ry * 10;
            int4 v = *(const int4*)(pp + (size_t)(y0 - 2 + ry) * W_ + (x0 - 4) + 4 * c4);
            *(int4*)&sPred[ry * 40 + 4 * c4] = v;
        }
    } else {
        for (int i = tid; i < 36 * 40; i += 256) {
            int ry = i / 40, c = i - ry * 40;
            int gy = y0 - 2 + ry, gx = x0 - 4 + c;
            sPred[i] = (gy >= 0 && gy < H_ && gx >= 0 && gx < W_) ? pp[(size_t)gy * W_ + gx] : -1;
        }
    }
    __syncthreads();

    // ---- identity check over tile+1 halo (34x34 px) ----
    const int lane = tid & 63, wv = tid >> 6;
    unsigned long long acc = 0ULL;
    for (int r = wv; r < TILE + 2; r += 4) {
        bool viol = false;
        if (lane < TILE + 2) {
            int gy = y0 - 1 + r, gx = x0 - 1 + lane;
            if (gy >= 0 && gy < H_ && gx >= 0 && gx < W_) {
                const int py = r + 1, px = lane + 3;          // sPred[36][40] frame
                int c  = sPred[py * 40 + px];
                int up = sPred[(py - 1) * 40 + px];
                int dn = sPred[(py + 1) * 40 + px];
                int lf = sPred[py * 40 + px - 1];
                int rt = sPred[py * 40 + px + 1];
                int ul = sPred[(py - 1) * 40 + px - 1];
                int ur = sPred[(py - 1) * 40 + px + 1];
                int dl = sPred[(py + 1) * 40 + px - 1];
                int dr = sPred[(py + 1) * 40 + px + 1];
                int mx = imax(imax(up, dn), imax(lf, rt));
                int Bv = 0x7fffffff;
                int mn = imin(imin(imin(up < 0 ? Bv : up, dn < 0 ? Bv : dn),
                                   imin(lf < 0 ? Bv : lf, rt < 0 ? Bv : rt)),
                              imin(imin(ul < 0 ? Bv : ul, ur < 0 ? Bv : ur),
                                   imin(dl < 0 ? Bv : dl, dr < 0 ? Bv : dr)));
                viol = !((mx > c) || (mn < c));
            }
        }
        acc |= __ballot(viol);
    }
    if (lane == 0) sV[wv] = (acc != 0ULL) ? 1 : 0;
    __syncthreads();
    const bool dirty = (sV[0] | sV[1] | sV[2] | sV[3]) != 0;

    const int tileId = (((blockIdx.z << 4) + blockIdx.y) << 5) + blockIdx.x;
    if (!dirty) {
        if (flags) {
            if (tid == 0) flags[tileId] = 0;
        } else {
            int ty = tid >> 3, tx4 = (tid & 7) * 4;
            const float4 v = *(const float4*)(xp + (size_t)(y0 + ty) * W_ + (x0 + tx4));
            *(float4*)(op + (size_t)(y0 + ty) * W_ + (x0 + tx4)) = v;
        }
        return;
    }

    // =================== general path (rare; validated r2-r5) ===================
    __syncthreads();
    for (int i = tid; i < RP * RP; i += 256) {
        int ry = i / RP, rx = i - ry * RP;
        int gy = y0 - HP + ry, gx = x0 - HP + rx;
        sPred[i] = (gy >= 0 && gy < H_ && gx >= 0 && gx < W_) ? pp[(size_t)gy * W_ + gx] : -1;
    }
    for (int i = tid; i < RD * RD; i += 256) {
        int ry = i / RD, rx = i - ry * RD;
        int gy = clampi(y0 - HD + ry, 0, H_ - 1);
        int gx = clampi(x0 - HD + rx, 0, W_ - 1);
        sA[i] = xp[(size_t)gy * W_ + gx];
    }
    __syncthreads();

    {   // b0 via ballot
        for (int row = wv; row < RB; row += 4) {
            bool bp = false;
            if (lane < RB) {
                const int py = row + 1, px = lane + 1;
                int c = sPred[py * RP + px];
                if (c >= 0) {
                    int up = sPred[(py - 1) * RP + px];
                    int dn = sPred[(py + 1) * RP + px];
                    int lf = sPred[py * RP + px - 1];
                    int rt = sPred[py * RP + px + 1];
                    int ul = sPred[(py - 1) * RP + px - 1];
                    int ur = sPred[(py - 1) * RP + px + 1];
                    int dl = sPred[(py + 1) * RP + px - 1];
                    int dr = sPred[(py + 1) * RP + px + 1];
                    int mx = imax(imax(up, dn), imax(lf, rt));
                    int Bv = 0x7fffffff;
                    int mn = imin(imin(imin(up < 0 ? Bv : up, dn < 0 ? Bv : dn),
                                       imin(lf < 0 ? Bv : lf, rt < 0 ? Bv : rt)),
                                  imin(imin(ul < 0 ? Bv : ul, ur < 0 ? Bv : ur),
                                       imin(dl < 0 ? Bv : dl, dr < 0 ? Bv : dr)));
                    bp = (mx > c) || (mn < c);
                }
            }
            unsigned long long bal = __ballot(bp);
            if (lane == 0) sB[0][row] = bal;
        }
    }

    #pragma unroll
    for (int lvl = 1; lvl < 4; ++lvl) {
        __syncthreads();
        if (tid < RB) {
            unsigned long long c = sB[lvl - 1][tid];
            unsigned long long u = (tid > 0)      ? sB[lvl - 1][tid - 1] : 0ULL;
            unsigned long long d = (tid < RB - 1) ? sB[lvl - 1][tid + 1] : 0ULL;
            sB[lvl][tid] = c | (c << 1) | (c >> 1) | u | d;
        }
    }
    __syncthreads();

    if (borderB) {
        const bool act = tid < 4 * RB;
        unsigned long long val = 0; int lvl = 0, row = 0;
        if (act) {
            lvl = tid / RB; row = tid - lvl * RB;
            int srcRow = clampi(row, topB ? HB : 0, botB ? (RB - 1 - HB) : RB - 1);
            val = sB[lvl][srcRow];
            if (leftB) {
                unsigned long long b = (val >> HB) & 1ULL;
                unsigned long long lo = (1ULL << HB) - 1;
                val = (val & ~lo) | (b ? lo : 0ULL);
            }
            if (rightB) {
                const int jb = RB - 1 - HB;
                unsigned long long b = (val >> jb) & 1ULL;
                unsigned long long keep = (1ULL << (jb + 1)) - 1;
                unsigned long long hi = (((1ULL << RB) - 1) & ~keep);
                val = (val & keep) | (b ? hi : 0ULL);
            }
        }
        __syncthreads();
        if (act) sB[lvl][row] = val;
    }
    __syncthreads();

    float* cur = sA;
    float* nxt = sC;
    #pragma unroll
    for (int it = 0; it < 4; ++it) {
        const int r = 3 - it;
        const unsigned long long* br = sB[r];

        for (int i = tid; i < RD * RD; i += 256) {
            int ry = i / RD, rx = i - ry * RD;
            unsigned long long row = br[ry + (HB - HD)];
            int rxm = rx > 0 ? rx - 1 : 0;
            int rxp = rx < RD - 1 ? rx + 1 : RD - 1;
            float m0 = ((row >> (rx + 2)) & 1ULL) ? 0.f : 1.f;
            float m1 = ((row >> (rx + 3)) & 1ULL) ? 0.f : 1.f;
            float m2 = ((row >> (rx + 4)) & 1ULL) ? 0.f : 1.f;
            float a0 = cur[ry * RD + rxm];
            float a1 = cur[ry * RD + rx];
            float a2 = cur[ry * RD + rxp];
            sHX[i] = m0 * a0 + m1 * a1 + m2 * a2;
            sHM[i] = m0 + m1 + m2;
        }
        __syncthreads();

        for (int i = tid; i < 38 * 38; i += 256) {
            int q = i / 38;
            int ry = 1 + q, rx = 1 + (i - q * 38);
            int idx = ry * RD + rx;
            float n = sHM[idx - RD] + sHM[idx] + sHM[idx + RD];
            float y = sHX[idx - RD] + sHX[idx] + sHX[idx + RD];
            float c = cur[idx];
            unsigned long long row = br[ry + (HB - HD)];
            bool masked = ((row >> (rx + 3)) & 1ULL) != 0ULL;
            float avg = y * __builtin_amdgcn_rcpf(n);
            nxt[idx] = (masked && n > 0.5f) ? avg : c;
        }
        __syncthreads();

        if (borderB) {
            for (int i = tid; i < RD * RD; i += 256) {
                int ry = i / RD, rx = i - ry * RD;
                int ryc = clampi(ry, topB ? HD : 0, botB ? (RD - 1 - HD) : RD - 1);
                int rxc = clampi(rx, leftB ? HD : 0, rightB ? (RD - 1 - HD) : RD - 1);
                if (ryc != ry || rxc != rx) nxt[i] = nxt[ryc * RD + rxc];
            }
        }
        __syncthreads();
        float* t = cur; cur = nxt; nxt = t;
    }

    for (int i = tid; i < TILE * TILE; i += 256) {
        int ty = i >> 5, tx = i & 31;
        op[(size_t)(y0 + ty) * W_ + (x0 + tx)] = cur[(ty + HD) * RD + (tx + HD)];
    }
    if (flags && tid == 0) flags[tileId] = 1;
}

// ---------------- Gaussian weights ----------------
#define GW0 0.39905027965f
#define GW1 0.24203622800f
#define GW2 0.05400558260f
#define GW3 0.00443304810f

// Fused H+V dilated Gaussian. Block = 64 rows x 128 cols output band.
// H-pass reads x (or mid where a tile is dirty) from global into LDS, V-pass from LDS.
__global__ __launch_bounds__(256)
void gaussF(const float* __restrict__ xg, const float* __restrict__ midg,
            const unsigned char* __restrict__ flags, float* __restrict__ outg)
{
    __shared__ float sH[100][128];   // 51.2 KB
    __shared__ int sDirty;

    const int tid = threadIdx.x;
    const int x0 = blockIdx.x * 128;
    const int y0 = blockIdx.y * 64;
    const int img = blockIdx.z;
    const size_t plane = (size_t)H_ * W_;
    const float* xp = xg  + (size_t)img * plane;
    float*       op = outg + (size_t)img * plane;

    if (tid == 0) sDirty = 0;
    __syncthreads();
    {   // any dirty tile within tap reach?
        const int tyLo = ((y0 >= 18) ? y0 - 18 : 0) >> 5;
        const int tyHi = ((y0 + 81 < H_) ? y0 + 81 : H_ - 1) >> 5;
        const int txLo = ((x0 >= 18) ? x0 - 18 : 0) >> 5;
        const int txHi = ((x0 + 145 < W_) ? x0 + 145 : W_ - 1) >> 5;
        const int ntx = txHi - txLo + 1;
        const int n = (tyHi - tyLo + 1) * ntx;
        if (tid < 64) {
            bool d = false;
            if (tid < n) {
                int q = tid / ntx;
                int ty = tyLo + q, tx = txLo + (tid - q * ntx);
                d = flags[(((img << 4) + ty) << 5) + tx] != 0;
            }
            unsigned long long bal = __ballot(d);
            if (tid == 0 && bal != 0ULL) sDirty = 1;
        }
    }
    __syncthreads();

    if (!sDirty) {
        // ---- clean H: vectorized reads of x only ----
        for (int i = tid; i < 100 * 32; i += 256) {
            int row = i >> 5, cg = i & 31;
            int gx0 = x0 + cg * 4;
            int gy = clampi(y0 - 18 + row, 0, H_ - 1);
            const float* rp = xp + (size_t)gy * W_;
            float4 o;
            if (gx0 >= 20 && gx0 <= 1000) {
                const float4* vp = (const float4*)(rp + gx0 - 20);
                float4 fm5 = vp[0], fm4 = vp[1], fm3 = vp[2], fm2 = vp[3], fm1 = vp[4];
                float4 f0 = vp[5], f1 = vp[6], f2 = vp[7], f3 = vp[8], f4 = vp[9], f5 = vp[10];
                o.x = GW0 * f0.x + GW1 * (fm2.z + f1.z) + GW2 * (fm3.x + f3.x) + GW3 * (fm5.z + f4.z);
                o.y = GW0 * f0.y + GW1 * (fm2.w + f1.w) + GW2 * (fm3.y + f3.y) + GW3 * (fm5.w + f4.w);
                o.z = GW0 * f0.z + GW1 * (fm1.x + f2.x) + GW2 * (fm3.z + f3.z) + GW3 * (fm4.x + f5.x);
                o.w = GW0 * f0.w + GW1 * (fm1.y + f2.y) + GW2 * (fm3.w + f3.w) + GW3 * (fm4.y + f5.y);
            } else {
                float r4[4];
                #pragma unroll
                for (int j = 0; j < 4; ++j) {
                    int gx = gx0 + j;
                    r4[j] = GW3 * (rp[clampi(gx - 18, 0, W_ - 1)] + rp[clampi(gx + 18, 0, W_ - 1)])
                          + GW2 * (rp[clampi(gx - 12, 0, W_ - 1)] + rp[clampi(gx + 12, 0, W_ - 1)])
                          + GW1 * (rp[clampi(gx - 6,  0, W_ - 1)] + rp[clampi(gx + 6,  0, W_ - 1)])
                          + GW0 *  rp[gx];
                }
                o.x = r4[0]; o.y = r4[1]; o.z = r4[2]; o.w = r4[3];
            }
            *(float4*)&sH[row][cg * 4] = o;
        }
    } else {
        // ---- dirty H: per-tap select x vs mid by tile flag ----
        const float* mp = midg + (size_t)img * plane;
        for (int i = tid; i < 100 * 32; i += 256) {
            int row = i >> 5, cg = i & 31;
            int gy = clampi(y0 - 18 + row, 0, H_ - 1);
            const float* rx = xp + (size_t)gy * W_;
            const float* rm = mp + (size_t)gy * W_;
            const int frow = ((img << 4) + (gy >> 5)) << 5;
            float r4[4];
            #pragma unroll
            for (int j = 0; j < 4; ++j) {
                int gx = x0 + cg * 4 + j;
                float t[7];
                #pragma unroll
                for (int k = 0; k < 7; ++k) {
                    int q = clampi(gx + (k - 3) * 6, 0, W_ - 1);
                    t[k] = flags[frow + (q >> 5)] ? rm[q] : rx[q];
                }
                r4[j] = GW3 * (t[0] + t[6]) + GW2 * (t[1] + t[5]) + GW1 * (t[2] + t[4]) + GW0 * t[3];
            }
            float4 o; o.x = r4[0]; o.y = r4[1]; o.z = r4[2]; o.w = r4[3];
            *(float4*)&sH[row][cg * 4] = o;
        }
    }
    __syncthreads();

    // ---- V pass from LDS + coalesced store ----
    for (int i = tid; i < 64 * 32; i += 256) {
        int r = i >> 5, cg = i & 31;
        float4 a0 = *(const float4*)&sH[r][cg * 4];
        float4 a1 = *(const float4*)&sH[r + 6][cg * 4];
        float4 a2 = *(const float4*)&sH[r + 12][cg * 4];
        float4 a3 = *(const float4*)&sH[r + 18][cg * 4];
        float4 a4 = *(const float4*)&sH[r + 24][cg * 4];
        float4 a5 = *(const float4*)&sH[r + 30][cg * 4];
        float4 a6 = *(const float4*)&sH[r + 36][cg * 4];
        float4 o;
        o.x = GW3 * (a0.x + a6.x) + GW2 * (a1.x + a5.x) + GW1 * (a2.x + a4.x) + GW0 * a3.x;
        o.y = GW3 * (a0.y + a6.y) + GW2 * (a1.y + a5.y) + GW1 * (a2.y + a4.y) + GW0 * a3.y;
        o.z = GW3 * (a0.z + a6.z) + GW2 * (a1.z + a5.z) + GW1 * (a2.z + a4.z) + GW0 * a3.z;
        o.w = GW3 * (a0.w + a6.w) + GW2 * (a1.w + a5.w) + GW1 * (a2.w + a4.w) + GW0 * a3.w;
        *(float4*)(op + (size_t)(y0 + r) * W_ + (x0 + cg * 4)) = o;
    }
}

// fallback tiled stage2 (only if ws too small for plane+flags)
#define GTW 64
#define GTH 64
#define GHALO 18
#define GRH (GTH + 2*GHALO)

__global__ __launch_bounds__(256)
void bsws_stage2_tiled(const float* __restrict__ ing, float* __restrict__ outg)
{
    __shared__ float sHt[GRH][GTW];
    const int tid = threadIdx.x;
    const int x0 = blockIdx.x * GTW;
    const int y0 = blockIdx.y * GTH;
    const size_t plane = (size_t)H_ * W_;
    const float* ip = ing  + blockIdx.z * plane;
    float*       op = outg + blockIdx.z * plane;

    for (int i = tid; i < GRH * GTW; i += 256) {
        int row = i >> 6, col = i & 63;
        int gy = clampi(y0 - GHALO + row, 0, H_ - 1);
        const float* rowp = ip + (size_t)gy * W_;
        int gx = x0 + col;
        float acc = GW3 * (rowp[clampi(gx - 18, 0, W_ - 1)] + rowp[clampi(gx + 18, 0, W_ - 1)])
                  + GW2 * (rowp[clampi(gx - 12, 0, W_ - 1)] + rowp[clampi(gx + 12, 0, W_ - 1)])
                  + GW1 * (rowp[clampi(gx - 6,  0, W_ - 1)] + rowp[clampi(gx + 6,  0, W_ - 1)])
                  + GW0 *  rowp[gx];
        sHt[row][col] = acc;
    }
    __syncthreads();
    for (int i = tid; i < GTH * GTW; i += 256) {
        int ty = i >> 6, tx = i & 63;
        float acc = GW3 * (sHt[ty][tx]      + sHt[ty + 36][tx])
                  + GW2 * (sHt[ty + 6][tx]  + sHt[ty + 30][tx])
                  + GW1 * (sHt[ty + 12][tx] + sHt[ty + 24][tx])
                  + GW0 *  sHt[ty + 18][tx];
        op[(size_t)(y0 + ty) * W_ + (x0 + tx)] = acc;
    }
}

extern "C" void kernel_launch(void* const* d_in, const int* in_sizes, int n_in,
                              void* d_out, int out_size, void* d_ws, size_t ws_size,
                              hipStream_t stream) {
    const float* x    = (const float*)d_in[0];
    const int*   pred = (const int*)d_in[1];
    float*       out  = (float*)d_out;
    float*       mid  = (float*)d_ws;

    const size_t plane_bytes = (size_t)NPX * 4;
    const dim3 g1(W_ / TILE, H_ / TILE, B_);

    if (ws_size >= plane_bytes + 4096) {
        unsigned char* flags = (unsigned char*)d_ws + plane_bytes;
        k_stage1<<<g1, 256, 0, stream>>>(x, pred, mid, flags);
        gaussF<<<dim3(W_ / 128, H_ / 64, B_), 256, 0, stream>>>(x, mid, flags, out);
    } else {
        k_stage1<<<g1, 256, 0, stream>>>(x, pred, mid, nullptr);
        bsws_stage2_tiled<<<dim3(W_ / GTW, H_ / GTH, B_), dim3(256), 0, stream>>>(mid, out);
    }
}